// Round 1
// 91.287 us; speedup vs baseline: 1.0989x; 1.0989x over previous
//
#include <hip/hip_runtime.h>

// Inv2d: B=4, C=128, H=W=64, G=8 (16 ch/grp), K=7, dil=2, pad=6,
// reduce 128->32, span 32->392.
//
// Round 12: fuse ker_gen into inv_apply. The materialized ker tensor
// (12.8 MB bf16, written with 52 scattered 2B stores/thread, then re-read)
// is replaced by 8 MFMAs/wave inside the apply kernel: each (b,g,row-pair)
// block computes ker[49][128px] = W_g[49][32] x redT[32][128px] + bias
// straight into the kvs LDS buffer (fp32, no bf16 round-trip). Removes one
// launch and ~25.7 MB of intermediate traffic. Apply loop unchanged from
// the proven R10/R11 structure.

#define HW 4096   // 64*64
#define NC 128
#define NR 32
#define KK 49
#define PR 76     // padded rows (6+64+6)
#define PC 80     // padded cols (8+64+8, float4-aligned)
#define KSTR 136  // apply-loop LDS per-tap stride (2 rows x 68)

typedef __attribute__((ext_vector_type(8))) short short8;
typedef __attribute__((ext_vector_type(4))) float f32x4;

__device__ __forceinline__ unsigned short f2bf(float f) {
  unsigned int u = __float_as_uint(f);
  u = (u + 0x7fffu + ((u >> 16) & 1u)) >> 16;   // RNE
  return (unsigned short)u;
}

// ---------------------------------------------------------------- red_gen
__global__ __launch_bounds__(256) void red_gen(
    const float* __restrict__ x, const float* __restrict__ w_reduce,
    const float* __restrict__ b_reduce, unsigned short* __restrict__ red_bf,
    float* __restrict__ x_pad) {
  // grid: 256 = b(4) x row(64). Block: one 64-px row, all 32 outputs.
  // Also writes x_pad interior row + this block's share of border zeros.
  __shared__ float xs[NC][64];       // 32 KB
  int t = threadIdx.x;
  int blk = blockIdx.x;
  int b = blk >> 6;
  int row = blk & 63;
  int p0 = row * 64;

  // ---- border zeroing: 992 of batch-b's 63488 border float4s ----
  {
    float4 z = make_float4(0.f, 0.f, 0.f, 0.f);
    float* xpb0 = x_pad + (size_t)b * NC * PR * PC;
#pragma unroll
    for (int it = 0; it < 4; ++it) {
      int local = it * 256 + t;
      if (local < 992) {
        int f = row * 992 + local;       // 0..63487
        int plane = f / 496;
        int k = f - plane * 496;
        int d;
        if (k < 120) d = k;                       // rows 0..5 (all 20 f4)
        else if (k < 240) d = k - 120 + 70 * 20;  // rows 70..75
        else {
          int k2 = k - 240;                       // rows 6..69, side cols
          int rr = 6 + (k2 >> 2);
          int c4 = k2 & 3;                        // f4 col 0,1,18,19
          d = rr * 20 + ((c4 < 2) ? c4 : 16 + c4);
        }
        *(float4*)(xpb0 + (size_t)plane * PR * PC + d * 4) = z;
      }
    }
  }

  const float* xb = x + b * NC * HW + p0;
  float* xpb = x_pad + ((size_t)(b * NC) * PR + (row + 6)) * PC + 8;
  int fx = t & 15;
  int c0 = t >> 4;
#pragma unroll
  for (int r = 0; r < 8; ++r) {
    int c = c0 + 16 * r;
    float4 v = *(const float4*)(xb + c * HW + fx * 4);
    *(float4*)(&xs[c][fx * 4]) = v;
    *(float4*)(xpb + (size_t)c * PR * PC + fx * 4) = v;  // x_pad interior
  }
  __syncthreads();

  int px = t & 63;
  int quad = __builtin_amdgcn_readfirstlane(t >> 6);  // wave-uniform octet
  const float* wq = w_reduce + quad * 8 * NC;         // scalar (s_load) base

  float acc[8];
#pragma unroll
  for (int j = 0; j < 8; ++j) acc[j] = b_reduce[quad * 8 + j];

#pragma unroll 8
  for (int k = 0; k < NC; ++k) {
    float xk = xs[k][px];
#pragma unroll
    for (int j = 0; j < 8; ++j) acc[j] += xk * wq[j * NC + k];
  }

  // red^T bf16: [b][px][32 o], one 16B store (o-octet = quad*8..+7)
  union { short8 v; unsigned short u[8]; } pk;
#pragma unroll
  for (int j = 0; j < 8; ++j) pk.u[j] = f2bf(acc[j]);
  *(short8*)(red_bf + ((size_t)(b * HW) + p0 + px) * NR + quad * 8) = pk.v;
}

// ---------------------------------------------------------------- inv_fused
__global__ __launch_bounds__(256) void inv_fused(
    const float* __restrict__ x_pad, const unsigned short* __restrict__ red_bf,
    const float* __restrict__ w_span, const float* __restrict__ b_span,
    float* __restrict__ out) {
  // grid: 1024 = hpair(32) x g(8) x b(4)
  // Phase 1: 4 waves compute ker[49][128px] via MFMA into kvs (fp32).
  // Phase 2: apply loop (identical to R10/R11 inv_apply).
  __shared__ float kvs[KK * KSTR];   // 26.7 KB
  __shared__ short wlds[64 * NR];    // bf16 W tile, 4 KB (taps 49..63 = 0)
  __shared__ float bsl[64];

  int blk = blockIdx.x;
  int hp = blk & 31;
  int g = (blk >> 5) & 7;
  int b = blk >> 8;
  int tid = threadIdx.x;
  int h0 = hp * 2;
  int p0 = h0 * 64;                  // this block's 128-px slice

  // ---- stage W_g (fp32 -> bf16) + bias into LDS ----
  const float* wg = w_span + g * KK * NR;            // 1568 floats
#pragma unroll
  for (int it = 0; it < 8; ++it) {
    int idx = it * 256 + tid;
    wlds[idx] = (idx < KK * NR) ? (short)f2bf(wg[idx]) : (short)0;
  }
  if (tid < 64) bsl[tid] = (tid < KK) ? b_span[g * KK + tid] : 0.f;
  __syncthreads();

  int l = tid & 63;
  int wv = __builtin_amdgcn_readfirstlane(tid >> 6);  // wave id 0..3
  int quad = l >> 4;
  int mn = l & 15;

  // A-fragments: A[m=lane&15][k=quad*8+j] (same mapping as proven ker_gen)
  short8 af[4];
#pragma unroll
  for (int tt = 0; tt < 4; ++tt)
    af[tt] = *(const short8*)(&wlds[(tt * 16 + mn) * NR + quad * 8]);

  // bias as MFMA C-operand: C/D row = quad*4+reg, col = lane&15
  f32x4 ci[4];
#pragma unroll
  for (int tt = 0; tt < 4; ++tt) {
#pragma unroll
    for (int r = 0; r < 4; ++r) ci[tt][r] = bsl[tt * 16 + quad * 4 + r];
  }

  // wave wv covers px [p0 + wv*32, +32) in 2 n-tiles of 16 px
  const unsigned short* rb =
      red_bf + ((size_t)b * HW + p0 + wv * 32 + mn) * NR + quad * 8;
#pragma unroll
  for (int nt = 0; nt < 2; ++nt) {
    short8 bf = *(const short8*)(rb + (size_t)nt * 16 * NR);
    f32x4 d0 = __builtin_amdgcn_mfma_f32_16x16x32_bf16(af[0], bf, ci[0], 0, 0, 0);
    f32x4 d1 = __builtin_amdgcn_mfma_f32_16x16x32_bf16(af[1], bf, ci[1], 0, 0, 0);
    f32x4 d2 = __builtin_amdgcn_mfma_f32_16x16x32_bf16(af[2], bf, ci[2], 0, 0, 0);
    f32x4 d3 = __builtin_amdgcn_mfma_f32_16x16x32_bf16(af[3], bf, ci[3], 0, 0, 0);
    int pxl = wv * 32 + nt * 16 + mn;          // 0..127 (r is wave-uniform)
    int r = pxl >> 6, col = pxl & 63;
    float* dst = &kvs[r * 68 + col];
#pragma unroll
    for (int rg = 0; rg < 4; ++rg) {
      dst[(size_t)(0 * 16 + quad * 4 + rg) * KSTR] = d0[rg];
      dst[(size_t)(1 * 16 + quad * 4 + rg) * KSTR] = d1[rg];
      dst[(size_t)(2 * 16 + quad * 4 + rg) * KSTR] = d2[rg];
    }
    if (quad == 0) dst[(size_t)48 * KSTR] = d3[0];  // only tap 48
  }
  __syncthreads();

  // ---- phase 2: apply (unchanged) ----
  int c = tid >> 4;                  // channel in group
  int sub = tid & 15;
  int r = sub >> 3;                  // row 0..1
  int oct = sub & 7;                 // col octet
  int h = h0 + r;

  const float* xrow =
      x_pad + ((size_t)(b * NC + g * 16 + c) * PR + h) * PC + 8 * oct;
  float2 a0 = {0.f, 0.f}, a1 = {0.f, 0.f}, a2 = {0.f, 0.f}, a3 = {0.f, 0.f};

#pragma unroll
  for (int i = 0; i < 7; ++i) {
    const float* pr = xrow + 2 * i * PC;
    float xr[24];
#pragma unroll
    for (int m = 0; m < 6; ++m) {
      float4 v = *(const float4*)(pr + 4 * m);
      xr[4 * m] = v.x; xr[4 * m + 1] = v.y;
      xr[4 * m + 2] = v.z; xr[4 * m + 3] = v.w;
    }
#pragma unroll
    for (int j = 0; j < 7; ++j) {
      const float* kb = &kvs[(i * 7 + j) * KSTR + r * 68 + 8 * oct];
      float4 k0 = *(const float4*)(kb);
      float4 k1 = *(const float4*)(kb + 4);
      a0.x = fmaf(xr[2 + 2 * j], k0.x, a0.x);
      a0.y = fmaf(xr[3 + 2 * j], k0.y, a0.y);
      a1.x = fmaf(xr[4 + 2 * j], k0.z, a1.x);
      a1.y = fmaf(xr[5 + 2 * j], k0.w, a1.y);
      a2.x = fmaf(xr[6 + 2 * j], k1.x, a2.x);
      a2.y = fmaf(xr[7 + 2 * j], k1.y, a2.y);
      a3.x = fmaf(xr[8 + 2 * j], k1.z, a3.x);
      a3.y = fmaf(xr[9 + 2 * j], k1.w, a3.y);
    }
  }

  float* op = out + (size_t)(b * NC + g * 16 + c) * HW + h * 64 + 8 * oct;
  *(float4*)op = make_float4(a0.x, a0.y, a1.x, a1.y);
  *(float4*)(op + 4) = make_float4(a2.x, a2.y, a3.x, a3.y);
}

extern "C" void kernel_launch(void* const* d_in, const int* in_sizes, int n_in,
                              void* d_out, int out_size, void* d_ws, size_t ws_size,
                              hipStream_t stream) {
  const float* x        = (const float*)d_in[0];  // [4,128,64,64]
  const float* w_reduce = (const float*)d_in[1];  // [32,128]
  const float* b_reduce = (const float*)d_in[2];  // [32]
  const float* w_span   = (const float*)d_in[3];  // [392,32]
  const float* b_span   = (const float*)d_in[4];  // [392]
  float* out = (float*)d_out;                     // [4,128,64,64]

  unsigned short* red_bf = (unsigned short*)d_ws;        // 4*4096*32 bf16 = 1 MB
  float* x_pad = (float*)((char*)d_ws + (1 << 20));      // 4*128*76*80  = 12.5 MB

  red_gen<<<256, 256, 0, stream>>>(x, w_reduce, b_reduce, red_bf, x_pad);
  inv_fused<<<1024, 256, 0, stream>>>(x_pad, red_bf, w_span, b_span, out);
}